// Round 1
// baseline (9532.627 us; speedup 1.0000x reference)
//
#include <hip/hip_runtime.h>

#define T_MAX 256
#define BATCH 32
#define NC 64
#define BEAM 16
#define TOPK 4
#define NEG (-1.0e9f)
#define FLTMAX 3.402823466e+38f
#define NSC (BEAM + BEAM * NC)   // 1040 candidate scores

// Matches jnp.logaddexp: amax + log1p(exp(-|a-b|)) (no NaNs in this problem)
__device__ __forceinline__ float log_add_exp(float a, float b) {
    float m = fmaxf(a, b);
    float d = fabsf(a - b);
    return m + log1pf(expf(-d));
}

__global__ __launch_bounds__(64) void ctc_beam_kernel(
        const float* __restrict__ data,      // [T, B, C] logits
        const int*   __restrict__ data_len,  // [B]
        float*       __restrict__ out)       // [B*4 probs][B*4 lens][B*4*256 labels]
{
    const int b    = blockIdx.x;
    const int lane = threadIdx.x;

    __shared__ float lp[NC];
    __shared__ float ext[BEAM * NC];              // pre-merge extend scores
    __shared__ unsigned char mflag[BEAM * NC];    // (i,c) hash-matched an active beam
    __shared__ int mc[BEAM * BEAM];               // mc[j][i] = matched c or -1
    __shared__ float sc[NSC];                     // top-k candidate scores
    __shared__ float tot_s[BEAM];
    __shared__ float stpb_s[BEAM], stpnb_s[BEAM];
    __shared__ float pb_s[BEAM], pnb_s[BEAM];
    __shared__ unsigned int h1_s[BEAM], h2_s[BEAM];
    __shared__ int lens_s[BEAM], last_s[BEAM], act_s[BEAM];
    __shared__ unsigned short hist[T_MAX * BEAM]; // bits[11:8]=parent, bit7=stay, bits[6:0]=char
    __shared__ int ord4[TOPK];
    __shared__ float val4[TOPK];

    int len = data_len[b];
    if (len < 0) len = 0;
    if (len > T_MAX) len = T_MAX;

    // ---- initial beam state: beam 0 = empty prefix ----
    if (lane < BEAM) {
        pb_s[lane]  = (lane == 0) ? 0.0f : NEG;
        pnb_s[lane] = NEG;
        h1_s[lane] = 0u; h2_s[lane] = 0u;
        lens_s[lane] = 0; last_s[lane] = -1;
        act_s[lane] = (lane == 0) ? 1 : 0;
    }
    // first in-loop barrier publishes these

    for (int t = 0; t < len; ++t) {
        // ---- phase A: log_softmax of frame t (jax form: shifted - log(sum(exp(shifted)))) ----
        float x = data[(t * BATCH + b) * NC + lane];
        float mx = x;
        #pragma unroll
        for (int m = 1; m < 64; m <<= 1) mx = fmaxf(mx, __shfl_xor(mx, m, 64));
        float ex = expf(x - mx);
        float sum = ex;
        #pragma unroll
        for (int m = 1; m < 64; m <<= 1) sum += __shfl_xor(sum, m, 64);
        float lp_reg = (x - mx) - logf(sum);
        lp[lane] = lp_reg;
        __syncthreads();   // (a) lp + previous-step state visible

        // ---- phase 2: per-beam totals and stay candidates (lanes = beams) ----
        float st_pb_r = 0.f, st_pnb0_r = 0.f;
        if (lane < BEAM) {
            float tb = log_add_exp(pb_s[lane], pnb_s[lane]);
            tot_s[lane] = tb;
            st_pb_r   = tb + lp[0];
            st_pnb0_r = (lens_s[lane] > 0) ? (pnb_s[lane] + lp[last_s[lane]]) : NEG;
        }
        __syncthreads();   // (b) tot_s visible

        // ---- phase 3: extend candidates, lane = class c ----
        {
            const int c = lane;
            #pragma unroll 4
            for (int i = 0; i < BEAM; ++i) {
                float base = (c == last_s[i]) ? pb_s[i] : tot_s[i];
                float v = base + lp_reg;
                if (c == 0 || !act_s[i]) v = NEG;
                ext[i * NC + c] = v;
                mflag[i * NC + c] = 0;
            }
        }
        __syncthreads();   // (c) ext + mflag zeroed

        // ---- phase 4: hash matches via closed form: at most one c per (i,j) ----
        #pragma unroll
        for (int k = 0; k < 4; ++k) {
            int p = lane * 4 + k;          // 256 (i,j) pairs
            int i = p >> 4, j = p & 15;
            unsigned int c1 = h1_s[j] - h1_s[i] * 1000003u;
            unsigned int c2 = h2_s[j] - h2_s[i] * 69069u;
            int cm = -1;
            if (c1 == c2 && c1 >= 1u && c1 <= 64u && act_s[j]) {
                cm = (int)c1 - 1;
                mflag[i * NC + cm] = 1;    // benign same-value races
            }
            mc[j * BEAM + i] = cm;
        }
        __syncthreads();   // (d)

        // ---- phase 5: merged (duplicate-prefix fold) + stay totals ----
        float st_tot_r = -FLTMAX;
        if (lane < BEAM) {
            const int j = lane;
            float amax = NEG;
            #pragma unroll 4
            for (int i = 0; i < BEAM; ++i) {
                int c = mc[j * BEAM + i];
                if (c >= 0) amax = fmaxf(amax, ext[i * NC + c]);
            }
            float merged;
            if (amax > NEG) {
                float sm = 0.f;
                #pragma unroll 4
                for (int i = 0; i < BEAM; ++i) {   // ascending i == flat order
                    int c = mc[j * BEAM + i];
                    if (c >= 0) sm += expf(ext[i * NC + c] - amax);
                }
                merged = amax + logf(sm);
            } else {
                merged = NEG;  // exact: NEG+log(1024) rounds to NEG in f32
            }
            float st_pnb_r = log_add_exp(st_pnb0_r, merged);
            st_tot_r = log_add_exp(st_pb_r, st_pnb_r);
            stpb_s[j]  = st_pb_r;
            stpnb_s[j] = st_pnb_r;
            sc[j] = st_tot_r;
        }
        // ---- phase 6: post-merge extend scores into sc ----
        #pragma unroll 4
        for (int r = 0; r < BEAM; ++r) {
            int f = r * NC + lane;
            sc[BEAM + f] = mflag[f] ? NEG : ext[f];
        }
        __syncthreads();   // (e)

        // ---- phase 7: stable top-16 (desc value, ties -> lowest flat index) ----
        float sel_v = -FLTMAX; int sel_i = 0;
        for (int k = 0; k < BEAM; ++k) {
            float bv = -FLTMAX; int bi = 0x7FFFFFFF;
            for (int e2 = lane; e2 < NSC; e2 += 64) {
                float v = sc[e2];
                if (v > bv || (v == bv && e2 < bi)) { bv = v; bi = e2; }
            }
            #pragma unroll
            for (int m = 1; m < 64; m <<= 1) {
                float ov = __shfl_xor(bv, m, 64);
                int   oi = __shfl_xor(bi, m, 64);
                if (ov > bv || (ov == bv && oi < bi)) { bv = ov; bi = oi; }
            }
            if (lane == k) { sel_v = bv; sel_i = bi; }
            if (lane == 0) sc[bi] = -FLTMAX;
            __syncthreads();
        }

        // ---- phase 8: build new state ----
        int idx = sel_i;
        float val = sel_v;
        bool stay = idx < BEAM;
        int parent = stay ? idx : ((idx - BEAM) >> 6);
        parent &= 15;
        int cnew = stay ? 0 : ((idx - BEAM) & 63);
        float n_pb = 0.f, n_pnb = 0.f;
        unsigned n_h1 = 0u, n_h2 = 0u;
        int n_len = 0, n_last = 0, n_act = 0;
        unsigned short hrec = 0;
        if (lane < BEAM) {
            n_pb  = stay ? stpb_s[parent]  : NEG;
            n_pnb = stay ? stpnb_s[parent] : val;
            n_h1  = stay ? h1_s[parent] : (h1_s[parent] * 1000003u + (unsigned)(cnew + 1));
            n_h2  = stay ? h2_s[parent] : (h2_s[parent] * 69069u   + (unsigned)(cnew + 1));
            n_len = lens_s[parent] + (stay ? 0 : 1);
            n_last = stay ? last_s[parent] : cnew;
            n_act = (val > -5.0e8f) ? 1 : 0;   // vals > NEG/2
            hrec = (unsigned short)((parent << 8) | (stay ? 0x80 : 0) | cnew);
        }
        __syncthreads();   // (f) old-state reads complete
        if (lane < BEAM) {
            pb_s[lane] = n_pb;  pnb_s[lane] = n_pnb;
            h1_s[lane] = n_h1;  h2_s[lane] = n_h2;
            lens_s[lane] = n_len; last_s[lane] = n_last;
            act_s[lane] = n_act;
            hist[t * BEAM + lane] = hrec;
        }
        // next iteration's barrier (a) publishes the writes
    }
    __syncthreads();

    // ---- final stable top-4 over beam totals ----
    float ft = (lane < BEAM) ? log_add_exp(pb_s[lane], pnb_s[lane]) : -FLTMAX;
    int fidx = (lane < BEAM) ? lane : 0x7FFFFFFF;
    for (int k = 0; k < TOPK; ++k) {
        float bv = ft; int bi = fidx;
        #pragma unroll
        for (int m = 1; m < 64; m <<= 1) {
            float ov = __shfl_xor(bv, m, 64);
            int   oi = __shfl_xor(bi, m, 64);
            if (ov > bv || (ov == bv && oi < bi)) { bv = ov; bi = oi; }
        }
        if (lane == 0) { ord4[k] = bi; val4[k] = bv; }
        if (lane == bi) ft = -FLTMAX;   // remove winner (it lives in its own lane)
    }
    __syncthreads();

    // ---- outputs: probs [B,4] | lens [B,4] | labels [B,4,256], all as f32 values ----
    for (int e2 = lane; e2 < TOPK * T_MAX; e2 += 64)
        out[BATCH * TOPK * 2 + b * (TOPK * T_MAX) + e2] = -1.0f;
    __syncthreads();
    if (lane < TOPK) {
        const int k = lane;
        const int bi = ord4[k];
        out[b * TOPK + k] = -val4[k];
        out[BATCH * TOPK + b * TOPK + k] = (float)lens_s[bi];
        int pos = lens_s[bi] - 1;
        int cur = bi;
        float* lab = out + BATCH * TOPK * 2 + b * (TOPK * T_MAX) + k * T_MAX;
        for (int tt = len - 1; tt >= 0; --tt) {
            unsigned short h = hist[tt * BEAM + cur];
            if (!(h & 0x80)) { lab[pos] = (float)(h & 0x7F); --pos; }
            cur = h >> 8;
        }
    }
}

extern "C" void kernel_launch(void* const* d_in, const int* in_sizes, int n_in,
                              void* d_out, int out_size, void* d_ws, size_t ws_size,
                              hipStream_t stream) {
    const float* data = (const float*)d_in[0];
    const int* data_len = (const int*)d_in[1];
    float* out = (float*)d_out;
    ctc_beam_kernel<<<dim3(BATCH), dim3(64), 0, stream>>>(data, data_len, out);
}

// Round 2
// 3037.909 us; speedup vs baseline: 3.1379x; 3.1379x over previous
//
#include <hip/hip_runtime.h>

#define T_MAX 256
#define BATCH 32
#define NC 64
#define BEAM 16
#define TOPK 4
#define NEG (-1.0e9f)
#define FLTMAX 3.402823466e+38f

typedef unsigned long long u64;
typedef unsigned int u32;

// Matches jnp.logaddexp exactly: max + log1p(exp(-|a-b|))
__device__ __forceinline__ float log_add_exp(float a, float b) {
    float m = fmaxf(a, b);
    float d = fabsf(a - b);
    return m + log1pf(expf(-d));
}

// Sortable key: monotone float map in bits [42:11], (2047 - flat_idx) in [10:0].
// Larger key == (larger value, then smaller flat index) -> lax.top_k stable order.
__device__ __forceinline__ u64 pack_key(float v, int flat) {
    u32 u = __float_as_uint(v);
    u32 k = (u & 0x80000000u) ? ~u : (u | 0x80000000u);
    return ((u64)k << 11) | (u64)(2047 - flat);
}
__device__ __forceinline__ float key_val(u64 key) {
    u32 k = (u32)(key >> 11);
    u32 u = (k & 0x80000000u) ? (k ^ 0x80000000u) : ~k;
    return __uint_as_float(u);
}
__device__ __forceinline__ int key_flat(u64 key) {
    return 2047 - (int)(key & 2047u);
}
__device__ __forceinline__ u64 max64(u64 a, u64 b) { return a > b ? a : b; }

// Fully parallel log-softmax precompute: one 64-lane block per (t,b) row.
// Butterfly order identical to the in-loop variant (bit-exact).
__global__ __launch_bounds__(64) void softmax_kernel(const float* __restrict__ data,
                                                     float* __restrict__ lp_out) {
    const int row = blockIdx.x;
    const int lane = threadIdx.x;
    float x = data[row * NC + lane];
    float mx = x;
    #pragma unroll
    for (int m = 1; m < 64; m <<= 1) mx = fmaxf(mx, __shfl_xor(mx, m, 64));
    float sum = expf(x - mx);
    #pragma unroll
    for (int m = 1; m < 64; m <<= 1) sum += __shfl_xor(sum, m, 64);
    lp_out[row * NC + lane] = (x - mx) - logf(sum);
}

template <bool PRE>
__global__ __launch_bounds__(64) void ctc_beam_kernel(
        const float* __restrict__ data,      // [T, B, C] logits
        const float* __restrict__ lp_pre,    // [T, B, C] precomputed log-probs (if PRE)
        const int*   __restrict__ data_len,  // [B]
        float*       __restrict__ out)       // [B*4 probs][B*4 lens][B*4*256 labels]
{
    const int b    = blockIdx.x;
    const int lane = threadIdx.x;

    __shared__ u32 mmask[BEAM * 2];               // per-i 64-bit (i,c) match mask
    __shared__ unsigned short hist[T_MAX * BEAM]; // [11:8]=parent, bit7=stay, [6:0]=char
    __shared__ int ord4[TOPK];
    __shared__ float val4[TOPK];

    int len = data_len[b];
    if (len < 0) len = 0;
    if (len > T_MAX) len = T_MAX;

    // ---- beam state in registers (meaningful in lanes < 16) ----
    float pb  = (lane == 0) ? 0.0f : NEG;
    float pnb = NEG;
    u32 h1 = 0u, h2 = 0u;
    int lenb = 0, lastb = -1, actb = (lane == 0) ? 1 : 0;

    // prefetch row 0
    const float* src = PRE ? lp_pre : data;
    float xpref = (len > 0) ? src[b * NC + lane] : 0.f;

    #pragma unroll 1
    for (int t = 0; t < len; ++t) {
        float x = xpref;
        int tn = (t + 1 < len) ? (t + 1) : t;
        xpref = src[(tn * BATCH + b) * NC + lane];   // prefetch next row early

        float lp;
        if (PRE) {
            lp = x;
        } else {
            float mx = x;
            #pragma unroll
            for (int m = 1; m < 64; m <<= 1) mx = fmaxf(mx, __shfl_xor(mx, m, 64));
            float sum = expf(x - mx);
            #pragma unroll
            for (int m = 1; m < 64; m <<= 1) sum += __shfl_xor(sum, m, 64);
            lp = (x - mx) - logf(sum);
        }
        float lp0 = __shfl(lp, 0, 64);

        // ---- stay candidates (lanes < 16 meaningful) ----
        float tot = log_add_exp(pb, pnb);
        int lastc = (lastb < 0) ? 0 : (lastb & 63);
        float lplast = __shfl(lp, lastc, 64);        // per-lane bpermute
        float st_pb   = tot + lp0;
        float st_pnb0 = (lenb > 0) ? (pnb + lplast) : NEG;

        // ---- hash matches (closed form: at most one c per (i,j)) ----
        // lane j holds cm[i] = matched class or -1
        if (lane < BEAM * 2) mmask[lane] = 0u;
        int cm[BEAM];
        bool anym_l = false;
        #pragma unroll
        for (int i = 0; i < BEAM; ++i) {
            u32 h1i = __shfl(h1, i, 64);             // const lane -> readlane/SGPR
            u32 h2i = __shfl(h2, i, 64);
            u32 c1 = h1 - h1i * 1000003u;
            u32 c2 = h2 - h2i * 69069u;
            int cmv = -1;
            if (lane < BEAM && actb && c1 == c2 && c1 >= 1u && c1 <= 64u)
                cmv = (int)c1 - 1;
            cm[i] = cmv;
            anym_l = anym_l || (cmv >= 0);
        }
        u64 anym = __ballot(anym_l);                 // wave-uniform
        unsigned short mybits = 0;
        if (anym) {
            __syncthreads();                          // zero visible before OR
            #pragma unroll
            for (int i = 0; i < BEAM; ++i)
                if (cm[i] >= 0)
                    atomicOr(&mmask[i * 2 + (cm[i] >> 5)], 1u << (cm[i] & 31));
            __syncthreads();                          // ORs visible before read
            const int half = lane >> 5;
            const int bit  = lane & 31;
            #pragma unroll
            for (int i = 0; i < BEAM; ++i)
                mybits |= (unsigned short)(((mmask[i * 2 + half] >> bit) & 1u) << i);
        }

        // ---- extend candidates + merge gathers + key build (lane = class c) ----
        float amax = NEG;
        float vmerge[BEAM];
        u64 key[BEAM];
        #pragma unroll
        for (int i = 0; i < BEAM; ++i) {
            float tot_i = __shfl(tot, i, 64);
            float pb_i  = __shfl(pb, i, 64);
            int   la_i  = __shfl((lastb << 1) | (actb & 1), i, 64);
            int last_i = la_i >> 1;
            int act_i  = la_i & 1;
            float e0 = ((lane == last_i) ? pb_i : tot_i) + lp;
            if (lane == 0 || !act_i) e0 = NEG;       // blank / inactive
            int gsrc = (cm[i] >= 0) ? cm[i] : 0;
            float vi = __shfl(e0, gsrc, 64);          // full-exec bpermute gather
            vmerge[i] = vi;
            if (cm[i] >= 0) amax = fmaxf(amax, vi);
            float ev = ((mybits >> i) & 1) ? NEG : e0;
            key[i] = pack_key(ev, BEAM + i * NC + lane);
        }
        float merged = NEG;
        if (anym) {
            if (amax > NEG) {                         // per-lane; rare
                float sm = 0.f;
                #pragma unroll
                for (int i = 0; i < BEAM; ++i)
                    if (cm[i] >= 0) sm += expf(vmerge[i] - amax);
                merged = amax + logf(sm);
            }
        }
        float st_pnb = log_add_exp(st_pnb0, merged);
        float st_tot = log_add_exp(st_pb, st_pnb);
        u64 kstay = (lane < BEAM) ? pack_key(st_tot, lane) : 0ull;

        // ---- stable top-16: register-resident iterative extraction ----
        u64 prev = ~0ull;
        u64 selkey = 0ull;
        #pragma unroll 1
        for (int r = 0; r < BEAM; ++r) {
            u64 cand = (kstay < prev) ? kstay : 0ull;
            #pragma unroll
            for (int s = 0; s < BEAM; ++s) {
                u64 ks = key[s];
                u64 f = (ks < prev) ? ks : 0ull;
                cand = max64(cand, f);
            }
            #pragma unroll
            for (int m = 1; m < 64; m <<= 1) {
                u64 o = (u64)__shfl_xor((long long)cand, m, 64);
                cand = max64(cand, o);
            }
            if (lane == r) selkey = cand;
            prev = cand;
        }

        // ---- new state (lane k takes round-k winner) ----
        int flat = key_flat(selkey);
        float val = key_val(selkey);
        bool stay = flat < BEAM;
        int pidx = stay ? flat : ((flat - BEAM) >> 6);
        pidx &= 15;
        int cnew = stay ? 0 : ((flat - BEAM) & 63);

        float g_stpb  = __shfl(st_pb, pidx, 64);     // full-exec gathers of old state
        float g_stpnb = __shfl(st_pnb, pidx, 64);
        u32   g_h1    = (u32)__shfl((int)h1, pidx, 64);
        u32   g_h2    = (u32)__shfl((int)h2, pidx, 64);
        int   g_len   = __shfl(lenb, pidx, 64);
        int   g_last  = __shfl(lastb, pidx, 64);

        pb   = stay ? g_stpb : NEG;
        pnb  = stay ? g_stpnb : val;
        h1   = stay ? g_h1 : (g_h1 * 1000003u + (u32)(cnew + 1));
        h2   = stay ? g_h2 : (g_h2 * 69069u   + (u32)(cnew + 1));
        lenb = g_len + (stay ? 0 : 1);
        lastb = stay ? g_last : cnew;
        actb = (val > -5.0e8f) ? 1 : 0;              // vals > NEG/2
        if (lane < BEAM)
            hist[t * BEAM + lane] =
                (unsigned short)((pidx << 8) | (stay ? 0x80 : 0) | cnew);
    }
    __syncthreads();

    // ---- final stable top-4 over beam totals ----
    float ft = (lane < BEAM) ? log_add_exp(pb, pnb) : -FLTMAX;
    int fidx = (lane < BEAM) ? lane : 0x7FFFFFFF;
    for (int k = 0; k < TOPK; ++k) {
        float bv = ft; int bi = fidx;
        #pragma unroll
        for (int m = 1; m < 64; m <<= 1) {
            float ov = __shfl_xor(bv, m, 64);
            int   oi = __shfl_xor(bi, m, 64);
            if (ov > bv || (ov == bv && oi < bi)) { bv = ov; bi = oi; }
        }
        if (lane == 0) { ord4[k] = bi; val4[k] = bv; }
        if (lane == bi) ft = -FLTMAX;
    }
    __syncthreads();

    // lens of selected beams via full-exec gather
    int bsel = ord4[lane & 3] & 15;
    int lensel = __shfl(lenb, bsel, 64);

    // ---- outputs: probs [B,4] | lens [B,4] | labels [B,4,256] ----
    for (int e2 = lane; e2 < TOPK * T_MAX; e2 += 64)
        out[BATCH * TOPK * 2 + b * (TOPK * T_MAX) + e2] = -1.0f;
    __syncthreads();
    if (lane < TOPK) {
        const int k = lane;
        out[b * TOPK + k] = -val4[k];
        out[BATCH * TOPK + b * TOPK + k] = (float)lensel;
        int pos = lensel - 1;
        int cur = ord4[k];
        float* lab = out + BATCH * TOPK * 2 + b * (TOPK * T_MAX) + k * T_MAX;
        for (int tt = len - 1; tt >= 0; --tt) {
            unsigned short h = hist[tt * BEAM + cur];
            if (!(h & 0x80)) { lab[pos] = (float)(h & 0x7F); --pos; }
            cur = h >> 8;
        }
    }
}

extern "C" void kernel_launch(void* const* d_in, const int* in_sizes, int n_in,
                              void* d_out, int out_size, void* d_ws, size_t ws_size,
                              hipStream_t stream) {
    const float* data = (const float*)d_in[0];
    const int* data_len = (const int*)d_in[1];
    float* out = (float*)d_out;
    const size_t lp_bytes = (size_t)T_MAX * BATCH * NC * sizeof(float);
    if (ws_size >= lp_bytes) {
        float* lp_ws = (float*)d_ws;
        softmax_kernel<<<dim3(T_MAX * BATCH), dim3(64), 0, stream>>>(data, lp_ws);
        ctc_beam_kernel<true><<<dim3(BATCH), dim3(64), 0, stream>>>(data, lp_ws, data_len, out);
    } else {
        ctc_beam_kernel<false><<<dim3(BATCH), dim3(64), 0, stream>>>(data, nullptr, data_len, out);
    }
}

// Round 3
// 2099.354 us; speedup vs baseline: 4.5407x; 1.4471x over previous
//
#include <hip/hip_runtime.h>

#define T_MAX 256
#define BATCH 32
#define NC 64
#define BEAM 16
#define TOPK 4
#define NEG (-1.0e9f)
#define FLTMAX 3.402823466e+38f

typedef unsigned long long u64;
typedef unsigned int u32;

// Matches jnp.logaddexp exactly: max + log1p(exp(-|a-b|))
__device__ __forceinline__ float log_add_exp(float a, float b) {
    float m = fmaxf(a, b);
    float d = fabsf(a - b);
    return m + log1pf(expf(-d));
}

// Sortable key: monotone float map in bits [42:11], (2047 - flat_idx) in [10:0].
// Larger key == (larger value, then smaller flat index) -> lax.top_k stable order.
// All real keys are > 0 (idx bits never all-zero), so 0 is a safe null.
__device__ __forceinline__ u64 pack_key(float v, int flat) {
    u32 u = __float_as_uint(v);
    u32 k = (u & 0x80000000u) ? ~u : (u | 0x80000000u);
    return ((u64)k << 11) | (u64)(2047 - flat);
}
__device__ __forceinline__ float key_val(u64 key) {
    u32 k = (u32)(key >> 11);
    u32 u = (k & 0x80000000u) ? (k ^ 0x80000000u) : ~k;
    return __uint_as_float(u);
}
__device__ __forceinline__ int key_flat(u64 key) {
    return 2047 - (int)(key & 2047u);
}
__device__ __forceinline__ u64 max64(u64 a, u64 b) { return a > b ? a : b; }
__device__ __forceinline__ u64 min64(u64 a, u64 b) { return a < b ? a : b; }

// Bitonic sort of 16 register-resident keys, descending. Pure VALU, fully unrolled.
__device__ __forceinline__ void sort16_desc(u64 (&a)[BEAM]) {
    #pragma unroll
    for (int k = 2; k <= 16; k <<= 1) {
        #pragma unroll
        for (int j = k >> 1; j > 0; j >>= 1) {
            #pragma unroll
            for (int i = 0; i < 16; ++i) {
                int l = i ^ j;
                if (l > i) {
                    const bool desc = ((i & k) == 0);   // compile-time after unroll
                    u64 x = a[i], y = a[l];
                    bool sw = desc ? (x < y) : (x > y);
                    a[i] = sw ? y : x;
                    a[l] = sw ? x : y;
                }
            }
        }
    }
}

// Fully parallel log-softmax precompute: one 64-lane block per (t,b) row.
// Butterfly order identical to the in-loop variant (bit-exact).
__global__ __launch_bounds__(64) void softmax_kernel(const float* __restrict__ data,
                                                     float* __restrict__ lp_out) {
    const int row = blockIdx.x;
    const int lane = threadIdx.x;
    float x = data[row * NC + lane];
    float mx = x;
    #pragma unroll
    for (int m = 1; m < 64; m <<= 1) mx = fmaxf(mx, __shfl_xor(mx, m, 64));
    float sum = expf(x - mx);
    #pragma unroll
    for (int m = 1; m < 64; m <<= 1) sum += __shfl_xor(sum, m, 64);
    lp_out[row * NC + lane] = (x - mx) - logf(sum);
}

template <bool PRE>
__global__ __launch_bounds__(64, 1) void ctc_beam_kernel(
        const float* __restrict__ data,      // [T, B, C] logits
        const float* __restrict__ lp_pre,    // [T, B, C] precomputed log-probs (if PRE)
        const int*   __restrict__ data_len,  // [B]
        float*       __restrict__ out)       // [B*4 probs][B*4 lens][B*4*256 labels]
{
    const int b    = blockIdx.x;
    const int lane = threadIdx.x;

    __shared__ u32 mmask[BEAM * 2];               // per-i 64-bit (i,c) match mask
    __shared__ unsigned short hist[T_MAX * BEAM]; // [11:8]=parent, bit7=stay, [6:0]=char
    __shared__ int ord4[TOPK];
    __shared__ float val4[TOPK];

    int len = data_len[b];
    if (len < 0) len = 0;
    if (len > T_MAX) len = T_MAX;

    // ---- beam state in registers (meaningful in lanes < 16) ----
    float pb  = (lane == 0) ? 0.0f : NEG;
    float pnb = NEG;
    u32 h1 = 0u, h2 = 0u;
    int lenb = 0, lastb = -1, actb = (lane == 0) ? 1 : 0;

    const float* src = PRE ? lp_pre : data;
    float xpref = (len > 0) ? src[b * NC + lane] : 0.f;   // prefetch row 0

    #pragma unroll 1
    for (int t = 0; t < len; ++t) {
        float x = xpref;
        int tn = (t + 1 < len) ? (t + 1) : t;
        xpref = src[(tn * BATCH + b) * NC + lane];   // prefetch next row early

        float lp;
        if (PRE) {
            lp = x;
        } else {
            float mx = x;
            #pragma unroll
            for (int m = 1; m < 64; m <<= 1) mx = fmaxf(mx, __shfl_xor(mx, m, 64));
            float sum = expf(x - mx);
            #pragma unroll
            for (int m = 1; m < 64; m <<= 1) sum += __shfl_xor(sum, m, 64);
            lp = (x - mx) - logf(sum);
        }
        float lp0 = __shfl(lp, 0, 64);

        // ---- stay candidates (lanes < 16 meaningful) ----
        float tot = log_add_exp(pb, pnb);
        int lastc = (lastb < 0) ? 0 : (lastb & 63);
        float lplast = __shfl(lp, lastc, 64);        // variable-lane bpermute
        float st_pb   = tot + lp0;
        float st_pnb0 = (lenb > 0) ? (pnb + lplast) : NEG;

        // ---- hash matches (closed form: at most one c per (i,j)) ----
        if (lane < BEAM * 2) mmask[lane] = 0u;
        int cm[BEAM];
        bool anym_l = false;
        #pragma unroll
        for (int i = 0; i < BEAM; ++i) {
            u32 h1i = __shfl(h1, i, 64);             // const lane -> v_readlane
            u32 h2i = __shfl(h2, i, 64);
            u32 c1 = h1 - h1i * 1000003u;
            u32 c2 = h2 - h2i * 69069u;
            int cmv = -1;
            if (lane < BEAM && actb && c1 == c2 && c1 >= 1u && c1 <= 64u)
                cmv = (int)c1 - 1;
            cm[i] = cmv;
            anym_l = anym_l || (cmv >= 0);
        }
        u64 anym = __ballot(anym_l);                 // wave-uniform
        unsigned short mybits = 0;
        if (anym) {
            __syncthreads();
            #pragma unroll
            for (int i = 0; i < BEAM; ++i)
                if (cm[i] >= 0)
                    atomicOr(&mmask[i * 2 + (cm[i] >> 5)], 1u << (cm[i] & 31));
            __syncthreads();
            const int half = lane >> 5;
            const int bit  = lane & 31;
            #pragma unroll
            for (int i = 0; i < BEAM; ++i)
                mybits |= (unsigned short)(((mmask[i * 2 + half] >> bit) & 1u) << i);
        }

        // ---- extend candidates + key build (lane = class c) ----
        u64 a[BEAM];
        float e0s[BEAM];
        #pragma unroll
        for (int i = 0; i < BEAM; ++i) {
            float tot_i = __shfl(tot, i, 64);
            float pb_i  = __shfl(pb, i, 64);
            int   la_i  = __shfl((lastb << 1) | (actb & 1), i, 64);
            int last_i = la_i >> 1;
            int act_i  = la_i & 1;
            float e0 = ((lane == last_i) ? pb_i : tot_i) + lp;
            if (lane == 0 || !act_i) e0 = NEG;       // blank / inactive
            e0s[i] = e0;
            float ev = ((mybits >> i) & 1) ? NEG : e0;
            a[i] = pack_key(ev, BEAM + i * NC + lane);
        }

        // ---- duplicate-prefix fold (rare path; gathers only when needed) ----
        float merged = NEG;
        if (anym) {
            float amax = NEG;
            float vm[BEAM];
            #pragma unroll
            for (int i = 0; i < BEAM; ++i) {
                int gsrc = (cm[i] >= 0) ? cm[i] : 0;
                vm[i] = __shfl(e0s[i], gsrc, 64);    // full-exec gather
                if (cm[i] >= 0) amax = fmaxf(amax, vm[i]);
            }
            if (amax > NEG) {                        // per-lane
                float sm = 0.f;
                #pragma unroll
                for (int i = 0; i < BEAM; ++i)       // ascending i == flat order
                    if (cm[i] >= 0) sm += expf(vm[i] - amax);
                merged = amax + logf(sm);
            }
        }
        float st_pnb = log_add_exp(st_pnb0, merged);
        float st_tot = log_add_exp(st_pb, st_pnb);

        // ---- parallel stable top-16 ----
        // 1) local sort of 16 ext keys (VALU only)
        sort16_desc(a);
        // 2) branch-free insert of stay key (null 0 in lanes >= 16 is a no-op)
        {
            u64 s = (lane < BEAM) ? pack_key(st_tot, lane) : 0ull;
            #pragma unroll
            for (int i = BEAM - 1; i >= 1; --i)
                a[i] = max64(a[i], min64(a[i - 1], s));
            a[0] = max64(a[0], s);
        }
        // 3) xor-butterfly merge: 6 levels, each one batch of independent shuffles
        #pragma unroll 1
        for (int m = 1; m < 64; m <<= 1) {
            u64 c_[BEAM];
            #pragma unroll
            for (int i = 0; i < BEAM; ++i) {
                u64 o = (u64)__shfl_xor((long long)a[BEAM - 1 - i], m, 64);
                c_[i] = max64(a[i], o);              // top-16 multiset of union (bitonic)
            }
            #pragma unroll
            for (int j = 8; j > 0; j >>= 1) {        // bitonic cleanup -> sorted desc
                #pragma unroll
                for (int i = 0; i < BEAM; ++i)
                    if ((i & j) == 0) {
                        u64 xk = c_[i], yk = c_[i | j];
                        bool sw = xk < yk;
                        c_[i]     = sw ? yk : xk;
                        c_[i | j] = sw ? xk : yk;
                    }
            }
            #pragma unroll
            for (int i = 0; i < BEAM; ++i) a[i] = c_[i];
        }
        // all lanes now hold the identical sorted top-16; lane k takes rank k
        u64 selkey = a[0];
        #pragma unroll
        for (int i = 1; i < BEAM; ++i)
            if (lane == i) selkey = a[i];

        // ---- new state (lane k = round-k winner) ----
        int flat = key_flat(selkey);
        float val = key_val(selkey);
        bool stay = flat < BEAM;
        int pidx = stay ? flat : ((flat - BEAM) >> 6);
        pidx &= 15;
        int cnew = stay ? 0 : ((flat - BEAM) & 63);

        float g_stpb  = __shfl(st_pb, pidx, 64);     // full-exec variable gathers
        float g_stpnb = __shfl(st_pnb, pidx, 64);
        u32   g_h1    = (u32)__shfl((int)h1, pidx, 64);
        u32   g_h2    = (u32)__shfl((int)h2, pidx, 64);
        int   g_ll    = __shfl((lenb << 8) | (lastb & 255), pidx, 64);
        int   g_len   = g_ll >> 8;
        int   g_last  = (int)((signed char)(g_ll & 255));

        pb   = stay ? g_stpb : NEG;
        pnb  = stay ? g_stpnb : val;
        h1   = stay ? g_h1 : (g_h1 * 1000003u + (u32)(cnew + 1));
        h2   = stay ? g_h2 : (g_h2 * 69069u   + (u32)(cnew + 1));
        lenb = g_len + (stay ? 0 : 1);
        lastb = stay ? g_last : cnew;
        actb = (val > -5.0e8f) ? 1 : 0;              // vals > NEG/2
        if (lane < BEAM)
            hist[t * BEAM + lane] =
                (unsigned short)((pidx << 8) | (stay ? 0x80 : 0) | cnew);
    }
    __syncthreads();

    // ---- final stable top-4 over beam totals ----
    float ft = (lane < BEAM) ? log_add_exp(pb, pnb) : -FLTMAX;
    int fidx = (lane < BEAM) ? lane : 0x7FFFFFFF;
    for (int k = 0; k < TOPK; ++k) {
        float bv = ft; int bi = fidx;
        #pragma unroll
        for (int m = 1; m < 64; m <<= 1) {
            float ov = __shfl_xor(bv, m, 64);
            int   oi = __shfl_xor(bi, m, 64);
            if (ov > bv || (ov == bv && oi < bi)) { bv = ov; bi = oi; }
        }
        if (lane == 0) { ord4[k] = bi; val4[k] = bv; }
        if (lane == bi) ft = -FLTMAX;
    }
    __syncthreads();

    // lens of selected beams via full-exec gather
    int bsel = ord4[lane & 3] & 15;
    int lensel = __shfl(lenb, bsel, 64);

    // ---- outputs: probs [B,4] | lens [B,4] | labels [B,4,256] ----
    for (int e2 = lane; e2 < TOPK * T_MAX; e2 += 64)
        out[BATCH * TOPK * 2 + b * (TOPK * T_MAX) + e2] = -1.0f;
    __syncthreads();
    if (lane < TOPK) {
        const int k = lane;
        out[b * TOPK + k] = -val4[k];
        out[BATCH * TOPK + b * TOPK + k] = (float)lensel;
        int pos = lensel - 1;
        int cur = ord4[k];
        float* lab = out + BATCH * TOPK * 2 + b * (TOPK * T_MAX) + k * T_MAX;
        for (int tt = len - 1; tt >= 0; --tt) {
            unsigned short h = hist[tt * BEAM + cur];
            if (!(h & 0x80)) { lab[pos] = (float)(h & 0x7F); --pos; }
            cur = h >> 8;
        }
    }
}

extern "C" void kernel_launch(void* const* d_in, const int* in_sizes, int n_in,
                              void* d_out, int out_size, void* d_ws, size_t ws_size,
                              hipStream_t stream) {
    const float* data = (const float*)d_in[0];
    const int* data_len = (const int*)d_in[1];
    float* out = (float*)d_out;
    const size_t lp_bytes = (size_t)T_MAX * BATCH * NC * sizeof(float);
    if (ws_size >= lp_bytes) {
        float* lp_ws = (float*)d_ws;
        softmax_kernel<<<dim3(T_MAX * BATCH), dim3(64), 0, stream>>>(data, lp_ws);
        ctc_beam_kernel<true><<<dim3(BATCH), dim3(64), 0, stream>>>(data, lp_ws, data_len, out);
    } else {
        ctc_beam_kernel<false><<<dim3(BATCH), dim3(64), 0, stream>>>(data, nullptr, data_len, out);
    }
}